// Round 9
// baseline (143.041 us; speedup 1.0000x reference)
//
#include <hip/hip_runtime.h>
#include <stdint.h>

// Problem constants (fixed by setup_inputs).
#define N_LIDAR   8192
#define M_QUERIES 32768   // 1024 rays * 32 samples
#define D_FEAT    128
#define BLOCK     256
#define QPB       64                       // queries owned per block
#define N_BLK     (M_QUERIES / QPB)        // 512 blocks = 2 per CU
#define QUAR      (N_LIDAR / 4)            // 2048 candidates per wave-quarter

// Filter slack (HW-proven at absmax 0 in round 8): worst-case
// |e_a - e_exact| <= ~1.8e-3; EPS2 = 0.008 keeps 2.2x margin.
#define EPS2 0.008f

typedef __attribute__((ext_vector_type(8)))  short bf16x8;
typedef __attribute__((ext_vector_type(16))) float f32x16;

// Workspace layout (2 MB of ws):
#define WS_KEYS  0                         // 32768 * 8  u64 exact argmin keys
#define WS_ATAB  262144                    // 32768 * 16 bf16 (32B rows)
#define WS_BTAB  1310720                   //  8192 * 16 bf16 (32B rows)
#define WS_QPK   1572864                   // 32768 float4 (x,y,z,qs)
#define WS_CPK   2097152                   //  8192 float4 (-2lx,-2ly,-2lz,ks)

// Order-preserving float->u32 map (and inverse) for min-reduction.
__device__ __forceinline__ unsigned mapf(float f) {
    unsigned u = __float_as_uint(f);
    return (u & 0x80000000u) ? ~u : (u | 0x80000000u);
}
__device__ __forceinline__ float unmapf(unsigned u) {
    return __uint_as_float((u & 0x80000000u) ? (u ^ 0x80000000u) : ~u);
}

// Split f32 into bf16 hi + bf16 lo (RNE).
__device__ __forceinline__ void bsplit(float v, short& h, short& l) {
    unsigned u = __float_as_uint(v);
    unsigned r = (u + 0x7FFFu + ((u >> 16) & 1u)) & 0xFFFF0000u;
    h = (short)(r >> 16);
    float lo = v - __uint_as_float(r);
    unsigned u2 = __float_as_uint(lo);
    l = (short)((u2 + 0x7FFFu + ((u2 >> 16) & 1u)) >> 16);
}

#define BF_ONE ((short)0x3F80)

// Prep: build MFMA A/B tables encoding e_a ~= -2*q.l + ks (argmin of d2 ==
// argmin of e; qs is per-query constant), rescore packs, init keys.
//   k0..2 : qx{h,h,l} * Lx{h,l,h}   (L = -2*l, exact power-of-2 scale)
//   k3..5 : qy...,  k6..8 : qz...,  k9,10 : 1 * ks{h,l},  k11..15 : 0
__global__ __launch_bounds__(BLOCK)
void prep_kernel(const float* __restrict__ pts, const float* __restrict__ lidar,
                 short* __restrict__ Atab, short* __restrict__ Btab,
                 float4* __restrict__ qpack, float4* __restrict__ cpack,
                 unsigned long long* __restrict__ keys) {
    #pragma clang fp contract(off)
    int i = blockIdx.x * blockDim.x + threadIdx.x;

    { // query side (all 32768)
        float x = pts[3 * i + 0], y = pts[3 * i + 1], z = pts[3 * i + 2];
        float qs = (x * x + y * y) + z * z;     // np rounding order, no FMA
        short xh, xl, yh, yl, zh, zl;
        bsplit(x, xh, xl); bsplit(y, yh, yl); bsplit(z, zh, zl);
        short a[16] = {xh, xh, xl, yh, yh, yl, zh, zh, zl,
                       BF_ONE, BF_ONE, 0, 0, 0, 0, 0};
        ((int4*)(Atab + 16 * i))[0] = *(const int4*)(a);
        ((int4*)(Atab + 16 * i))[1] = *(const int4*)(a + 8);
        qpack[i] = make_float4(x, y, z, qs);
        keys[i]  = 0xFFFFFFFFFFFFFFFFull;
    }
    if (i < N_LIDAR) {
        float lx = lidar[3 * i + 0], ly = lidar[3 * i + 1], lz = lidar[3 * i + 2];
        float ks = (lx * lx + ly * ly) + lz * lz;   // np rounding order
        float Lx = -2.0f * lx, Ly = -2.0f * ly, Lz = -2.0f * lz;  // exact
        short xh, xl, yh, yl, zh, zl, kh, kl;
        bsplit(Lx, xh, xl); bsplit(Ly, yh, yl); bsplit(Lz, zh, zl); bsplit(ks, kh, kl);
        short b[16] = {xh, xl, xh, yh, yl, yh, zh, zl, zh,
                       kh, kl, 0, 0, 0, 0, 0};
        ((int4*)(Btab + 16 * i))[0] = *(const int4*)(b);
        ((int4*)(Btab + 16 * i))[1] = *(const int4*)(b + 8);
        cpack[i] = make_float4(Lx, Ly, Lz, ks);
    }
}

// Exact reference-rounded rescore of one (query, candidate) pair (proven r1-r8).
__device__ __forceinline__ void rescore(int q, int c,
                                        const float4* __restrict__ qpack,
                                        const float4* __restrict__ cpack,
                                        unsigned long long* __restrict__ keys) {
    #pragma clang fp contract(off)
    float4 Q = qpack[q];
    float4 C = cpack[c];
    float cr = (Q.x * C.x + Q.y * C.y) + Q.z * C.z;  // = -2*cross, bit-exact
    float t  = Q.w + cr;                             // = fl(qs - 2*cross)
    float d2 = t + C.w;                              // = fl(t + ks)
    unsigned u = __float_as_uint(d2);
    u ^= (u >> 31) ? 0xFFFFFFFFu : 0x80000000u;
    unsigned long long key = ((unsigned long long)u << 13) | (unsigned)c;
    atomicMin(&keys[q], key);   // ties -> smaller index (np.argmin semantics)
}

// MFMA fragment addressing for v_mfma_f32_32x32x16_bf16 (HW-proven r5-r8):
//   A[m][k]: m = lane&31, k = (lane>>5)*8 + j
//   B[k][n]: n = lane&31, k = (lane>>5)*8 + j
//   C/D    : col = lane&31, row = (reg&3) + 8*(reg>>2) + 4*(lane>>5)
//
// Fused kernel: each block OWNS 64 queries and scans ALL 8192 candidates
// (wave w covers quarter [w*2048, (w+1)*2048)). No cross-block dependencies:
//   phase 1: approx min -> LDS sgmin (u32 ds_min), __syncthreads
//   phase 2: filtered exact rescore -> global keys (uncontended atomicMin)
//   phase 3: gather this block's 64 queries (keys read via AGENT atomic load,
//            which bypasses L1; only this block ever wrote them)
__global__ __launch_bounds__(BLOCK, 2)
void fused_kernel(const short* __restrict__ Atab, const short* __restrict__ Btab,
                  const float4* __restrict__ qpack, const float4* __restrict__ cpack,
                  unsigned long long* __restrict__ keys,
                  const float4* __restrict__ feat, float4* __restrict__ out) {
    __shared__ unsigned sgmin[QPB];
    const int tid  = threadIdx.x;
    const int lane = tid & 63, wave = tid >> 6;
    const int half = lane >> 5, ln = lane & 31;
    const int qbase   = blockIdx.x * QPB;
    const int segbase = wave * QUAR;

    if (tid < QPB) sgmin[tid] = 0xFFFFFFFFu;

    bf16x8 a0 = *(const bf16x8*)(Atab + (qbase + ln) * 16 + half * 8);
    bf16x8 a1 = *(const bf16x8*)(Atab + (qbase + 32 + ln) * 16 + half * 8);
    __syncthreads();

    // ---------- Phase 1: approx min over this wave's quarter ----------
    {
        f32x16 m0, m1;
        #pragma unroll
        for (int r = 0; r < 16; ++r) { m0[r] = __builtin_inff(); m1[r] = __builtin_inff(); }

        const short* bp = Btab + (segbase + ln) * 16 + half * 8;
        #pragma unroll 2
        for (int g = 0; g < QUAR / 32; ++g) {
            bf16x8 b = *(const bf16x8*)bp;
            bp += 32 * 16;
            f32x16 z = 0.0f;
            f32x16 acc  = __builtin_amdgcn_mfma_f32_32x32x16_bf16(a0, b, z, 0, 0, 0);
            f32x16 acc2 = __builtin_amdgcn_mfma_f32_32x32x16_bf16(a1, b, z, 0, 0, 0);
            #pragma unroll
            for (int r = 0; r < 16; ++r) m0[r] = fminf(m0[r], acc[r]);
            #pragma unroll
            for (int r = 0; r < 16; ++r) m1[r] = fminf(m1[r], acc2[r]);
        }
        #pragma unroll
        for (int off = 16; off >= 1; off >>= 1) {
            #pragma unroll
            for (int r = 0; r < 16; ++r) {
                m0[r] = fminf(m0[r], __shfl_xor(m0[r], off));
                m1[r] = fminf(m1[r], __shfl_xor(m1[r], off));
            }
        }
        if (ln == 0) {
            #pragma unroll
            for (int r = 0; r < 16; ++r) {
                int row = (r & 3) + 8 * (r >> 2) + 4 * half;
                atomicMin(&sgmin[row],      mapf(m0[r]));   // LDS ds_min_u32
                atomicMin(&sgmin[32 + row], mapf(m1[r]));
            }
        }
    }

    __syncthreads();

    // ---------- Phase 2: filtered exact rescore over the same quarter ----------
    {
        float thr0[16], thr1[16];
        #pragma unroll
        for (int r = 0; r < 16; ++r) {
            int row = (r & 3) + 8 * (r >> 2) + 4 * half;
            thr0[r] = unmapf(sgmin[row]) + EPS2;
            thr1[r] = unmapf(sgmin[32 + row]) + EPS2;
        }

        const short* bp = Btab + (segbase + ln) * 16 + half * 8;
        for (int g = 0; g < QUAR / 32; ++g) {
            bf16x8 b = *(const bf16x8*)bp;
            bp += 32 * 16;
            f32x16 z = 0.0f;
            f32x16 acc  = __builtin_amdgcn_mfma_f32_32x32x16_bf16(a0, b, z, 0, 0, 0);
            f32x16 acc2 = __builtin_amdgcn_mfma_f32_32x32x16_bf16(a1, b, z, 0, 0, 0);
            unsigned long long h0 = 0, h1 = 0;
            #pragma unroll
            for (int r = 0; r < 16; ++r) h0 |= __ballot(acc[r]  < thr0[r]);
            #pragma unroll
            for (int r = 0; r < 16; ++r) h1 |= __ballot(acc2[r] < thr1[r]);
            if (h0 | h1) {
                const int c = segbase + g * 32 + ln;
                unsigned mk0 = 0, mk1 = 0;
                #pragma unroll
                for (int r = 0; r < 16; ++r) mk0 = (acc[r]  < thr0[r]) ? (mk0 | (1u << r)) : mk0;
                #pragma unroll
                for (int r = 0; r < 16; ++r) mk1 = (acc2[r] < thr1[r]) ? (mk1 | (1u << r)) : mk1;
                while (mk0) {   // only hitting lanes iterate (exec-masked)
                    int r = __builtin_ctz(mk0); mk0 &= mk0 - 1;
                    rescore(qbase + (r & 3) + 8 * (r >> 2) + 4 * half, c,
                            qpack, cpack, keys);
                }
                while (mk1) {
                    int r = __builtin_ctz(mk1); mk1 &= mk1 - 1;
                    rescore(qbase + 32 + (r & 3) + 8 * (r >> 2) + 4 * half, c,
                            qpack, cpack, keys);
                }
            }
        }
    }

    __syncthreads();   // drains vmcnt: this block's key atomics are in L2

    // ---------- Phase 3: gather this block's 64 queries ----------
    // 64 queries x 32 float4 = 2048 float4; 256 threads x 8 each.
    #pragma unroll
    for (int e = 0; e < 8; ++e) {
        int elem = tid + e * BLOCK;            // 0..2047
        int q    = qbase + (elem >> 5);
        int l5   = elem & 31;
        unsigned long long key = __hip_atomic_load(&keys[q],
            __ATOMIC_RELAXED, __HIP_MEMORY_SCOPE_AGENT);   // L2 read, skips L1
        int idx = (int)(key & (unsigned long long)(N_LIDAR - 1));
        out[q * (D_FEAT / 4) + l5] = feat[idx * (D_FEAT / 4) + l5];
    }
}

extern "C" void kernel_launch(void* const* d_in, const int* in_sizes, int n_in,
                              void* d_out, int out_size, void* d_ws, size_t ws_size,
                              hipStream_t stream) {
    const float* pts      = (const float*)d_in[0];   // (1,1024,32,3)
    const float* lidar    = (const float*)d_in[1];   // (1,8192,3)
    const float* features = (const float*)d_in[2];   // (1,8192,128)
    float* out = (float*)d_out;                      // (1,1024,32,128)

    char* ws = (char*)d_ws;
    unsigned long long* keys = (unsigned long long*)(ws + WS_KEYS);
    short* Atab = (short*)(ws + WS_ATAB);
    short* Btab = (short*)(ws + WS_BTAB);
    float4* qpack = (float4*)(ws + WS_QPK);
    float4* cpack = (float4*)(ws + WS_CPK);

    prep_kernel<<<M_QUERIES / BLOCK, BLOCK, 0, stream>>>(
        pts, lidar, Atab, Btab, qpack, cpack, keys);
    fused_kernel<<<N_BLK, BLOCK, 0, stream>>>(
        Atab, Btab, qpack, cpack, keys,
        (const float4*)features, (float4*)out);
}

// Round 10
// 125.918 us; speedup vs baseline: 1.1360x; 1.1360x over previous
//
#include <hip/hip_runtime.h>
#include <stdint.h>

// Problem constants (fixed by setup_inputs).
#define N_LIDAR   8192
#define M_QUERIES 32768   // 1024 rays * 32 samples
#define D_FEAT    128
#define BLOCK     256
#define QPB       32                       // queries owned per block
#define N_BLK     (M_QUERIES / QPB)        // 1024 blocks = 4 per CU
#define QUAR      (N_LIDAR / 4)            // 2048 candidates per wave-quarter
#define GITER     (QUAR / 32)              // 64 MFMA tiles per wave per phase

// Filter slack (HW-proven at absmax 0 in round 8): worst-case
// |e_a - e_exact| <= ~1.8e-3; EPS2 = 0.008 keeps 2.2x margin.
#define EPS2 0.008f

typedef __attribute__((ext_vector_type(8)))  short bf16x8;
typedef __attribute__((ext_vector_type(16))) float f32x16;

// Workspace layout (640 KB of ws):
#define WS_KEYS  0                         // 32768 * 8  u64 exact argmin keys
#define WS_BTAB  262144                    //  8192 * 16 bf16 (32B rows)
#define WS_CPK   524288                    //  8192 float4 (-2lx,-2ly,-2lz,ks)

// Order-preserving float->u32 map (and inverse) for min-reduction.
__device__ __forceinline__ unsigned mapf(float f) {
    unsigned u = __float_as_uint(f);
    return (u & 0x80000000u) ? ~u : (u | 0x80000000u);
}
__device__ __forceinline__ float unmapf(unsigned u) {
    return __uint_as_float((u & 0x80000000u) ? (u ^ 0x80000000u) : ~u);
}

// Split f32 into bf16 hi + bf16 lo (RNE).
__device__ __forceinline__ void bsplit(float v, short& h, short& l) {
    unsigned u = __float_as_uint(v);
    unsigned r = (u + 0x7FFFu + ((u >> 16) & 1u)) & 0xFFFF0000u;
    h = (short)(r >> 16);
    float lo = v - __uint_as_float(r);
    unsigned u2 = __float_as_uint(lo);
    l = (short)((u2 + 0x7FFFu + ((u2 >> 16) & 1u)) >> 16);
}

#define BF_ONE ((short)0x3F80)

// Prep (lidar side only, 32 blocks): B table rows encoding the candidate
// side of e_a ~= -2*q.l + ks, plus exact-rescore pack.
//   k0..2 : qx{h,h,l} * Lx{h,l,h}   (L = -2*l, exact power-of-2 scale)
//   k3..5 : qy...,  k6..8 : qz...,  k9,10 : 1 * ks{h,l},  k11..15 : 0
__global__ __launch_bounds__(BLOCK)
void prep_kernel(const float* __restrict__ lidar,
                 short* __restrict__ Btab, float4* __restrict__ cpack) {
    #pragma clang fp contract(off)
    int i = blockIdx.x * blockDim.x + threadIdx.x;
    float lx = lidar[3 * i + 0], ly = lidar[3 * i + 1], lz = lidar[3 * i + 2];
    float ks = (lx * lx + ly * ly) + lz * lz;   // np rounding order, no FMA
    float Lx = -2.0f * lx, Ly = -2.0f * ly, Lz = -2.0f * lz;  // exact scale
    short xh, xl, yh, yl, zh, zl, kh, kl;
    bsplit(Lx, xh, xl); bsplit(Ly, yh, yl); bsplit(Lz, zh, zl); bsplit(ks, kh, kl);
    short b[16] = {xh, xl, xh, yh, yl, yh, zh, zl, zh,
                   kh, kl, 0, 0, 0, 0, 0};
    ((int4*)(Btab + 16 * i))[0] = *(const int4*)(b);
    ((int4*)(Btab + 16 * i))[1] = *(const int4*)(b + 8);
    cpack[i] = make_float4(Lx, Ly, Lz, ks);
}

// MFMA fragment addressing for v_mfma_f32_32x32x16_bf16 (HW-proven r5-r9):
//   A[m][k]: m = lane&31, k = (lane>>5)*8 + j
//   B[k][n]: n = lane&31, k = (lane>>5)*8 + j
//   C/D    : col = lane&31, row = (reg&3) + 8*(reg>>2) + 4*(lane>>5)
//
// Fused kernel: each block OWNS 32 queries; wave w scans candidate quarter
// [w*2048,(w+1)*2048). In-block query prep (A-frags via LDS), then:
//   phase 1: approx min -> LDS sgmin, __syncthreads
//   phase 2: filtered exact rescore -> global keys (only this block's keys)
//   phase 3: gather the block's 32 queries
// 1024 blocks x 256 thr, 4 blocks/CU -> 4 waves/SIMD for latency hiding;
// explicit B-prefetch keeps 2+ loads in flight per wave.
__global__ __launch_bounds__(BLOCK, 4)
void fused_kernel(const float* __restrict__ pts,
                  const short* __restrict__ Btab, const float4* __restrict__ cpack,
                  unsigned long long* __restrict__ keys,
                  const float4* __restrict__ feat, float4* __restrict__ out) {
    #pragma clang fp contract(off)
    __shared__ short   asplit[QPB][16];
    __shared__ float4  qpk[QPB];
    __shared__ unsigned sgmin[QPB];
    const int tid  = threadIdx.x;
    const int lane = tid & 63, wave = tid >> 6;
    const int half = lane >> 5, ln = lane & 31;
    const int qbase   = blockIdx.x * QPB;
    const int segbase = wave * QUAR;

    // ---- In-block query prep (32 threads) ----
    if (tid < QPB) {
        int q = qbase + tid;
        float x = pts[3 * q + 0], y = pts[3 * q + 1], z = pts[3 * q + 2];
        float qs = (x * x + y * y) + z * z;     // np rounding order, no FMA
        short xh, xl, yh, yl, zh, zl;
        bsplit(x, xh, xl); bsplit(y, yh, yl); bsplit(z, zh, zl);
        short a[16] = {xh, xh, xl, yh, yh, yl, zh, zh, zl,
                       BF_ONE, BF_ONE, 0, 0, 0, 0, 0};
        #pragma unroll
        for (int k = 0; k < 16; ++k) asplit[tid][k] = a[k];
        qpk[tid]   = make_float4(x, y, z, qs);
        sgmin[tid] = 0xFFFFFFFFu;
        // Key init: only this block ever touches keys[q]. Agent-scope atomic
        // store goes straight to the coherent point (skips L1).
        __hip_atomic_store(&keys[q], 0xFFFFFFFFFFFFFFFFull,
                           __ATOMIC_RELAXED, __HIP_MEMORY_SCOPE_AGENT);
    }
    __syncthreads();

    const bf16x8 a = *(const bf16x8*)&asplit[ln][half * 8];
    const int STR = 32 * 16;   // shorts per MFMA tile of B

    // ---------- Phase 1: approx min over this wave's quarter ----------
    {
        f32x16 m;
        #pragma unroll
        for (int r = 0; r < 16; ++r) m[r] = __builtin_inff();

        const short* bp = Btab + (segbase + ln) * 16 + half * 8;
        bf16x8 bcur = *(const bf16x8*)bp;
        #pragma unroll 2
        for (int g = 0; g < GITER - 1; ++g) {
            bf16x8 bnext = *(const bf16x8*)(bp + (g + 1) * STR);  // prefetch
            f32x16 z = 0.0f;
            f32x16 acc = __builtin_amdgcn_mfma_f32_32x32x16_bf16(a, bcur, z, 0, 0, 0);
            #pragma unroll
            for (int r = 0; r < 16; ++r) m[r] = fminf(m[r], acc[r]);
            bcur = bnext;
        }
        {
            f32x16 z = 0.0f;
            f32x16 acc = __builtin_amdgcn_mfma_f32_32x32x16_bf16(a, bcur, z, 0, 0, 0);
            #pragma unroll
            for (int r = 0; r < 16; ++r) m[r] = fminf(m[r], acc[r]);
        }

        // Butterfly min across the 32 lanes sharing each row.
        #pragma unroll
        for (int off = 16; off >= 1; off >>= 1) {
            #pragma unroll
            for (int r = 0; r < 16; ++r)
                m[r] = fminf(m[r], __shfl_xor(m[r], off));
        }
        if (ln == 0) {
            #pragma unroll
            for (int r = 0; r < 16; ++r) {
                int row = (r & 3) + 8 * (r >> 2) + 4 * half;
                atomicMin(&sgmin[row], mapf(m[r]));   // LDS ds_min_u32
            }
        }
    }

    __syncthreads();

    // ---------- Phase 2: filtered exact rescore over the same quarter ----------
    {
        float thr[16];
        #pragma unroll
        for (int r = 0; r < 16; ++r) {
            int row = (r & 3) + 8 * (r >> 2) + 4 * half;
            thr[r] = unmapf(sgmin[row]) + EPS2;
        }

        const short* bp = Btab + (segbase + ln) * 16 + half * 8;
        bf16x8 bcur = *(const bf16x8*)bp;
        for (int g = 0; g < GITER; ++g) {
            bf16x8 bnext;
            if (g < GITER - 1) bnext = *(const bf16x8*)(bp + (g + 1) * STR);
            f32x16 z = 0.0f;
            f32x16 acc = __builtin_amdgcn_mfma_f32_32x32x16_bf16(a, bcur, z, 0, 0, 0);
            bcur = bnext;
            unsigned long long h = 0;
            #pragma unroll
            for (int r = 0; r < 16; ++r) h |= __ballot(acc[r] < thr[r]);
            if (h) {
                const int c = segbase + g * 32 + ln;
                unsigned mk = 0;
                #pragma unroll
                for (int r = 0; r < 16; ++r)
                    mk = (acc[r] < thr[r]) ? (mk | (1u << r)) : mk;
                while (mk) {   // only hitting lanes iterate (exec-masked)
                    int r = __builtin_ctz(mk); mk &= mk - 1;
                    int row = (r & 3) + 8 * (r >> 2) + 4 * half;
                    // Exact reference-rounded rescore (proven r1-r9).
                    float4 Q = qpk[row];
                    float4 C = cpack[c];
                    float cr = (Q.x * C.x + Q.y * C.y) + Q.z * C.z; // = -2*cross
                    float t  = Q.w + cr;                            // fl(qs-2c)
                    float d2 = t + C.w;                             // fl(t+ks)
                    unsigned u = __float_as_uint(d2);
                    u ^= (u >> 31) ? 0xFFFFFFFFu : 0x80000000u;
                    unsigned long long key =
                        ((unsigned long long)u << 13) | (unsigned)c;
                    atomicMin(&keys[qbase + row], key);  // ties -> smaller idx
                }
            }
        }
    }

    __syncthreads();   // all this block's key atomics drained (vmcnt) + visible

    // ---------- Phase 3: gather this block's 32 queries ----------
    // 32 queries x 32 float4 = 1024 float4; 256 threads x 4 each.
    #pragma unroll
    for (int e = 0; e < 4; ++e) {
        int elem = tid + e * BLOCK;            // 0..1023
        int q    = qbase + (elem >> 5);
        int l5   = elem & 31;
        unsigned long long key = __hip_atomic_load(&keys[q],
            __ATOMIC_RELAXED, __HIP_MEMORY_SCOPE_AGENT);   // L2 read, skips L1
        int idx = (int)(key & (unsigned long long)(N_LIDAR - 1));
        out[q * (D_FEAT / 4) + l5] = feat[idx * (D_FEAT / 4) + l5];
    }
}

extern "C" void kernel_launch(void* const* d_in, const int* in_sizes, int n_in,
                              void* d_out, int out_size, void* d_ws, size_t ws_size,
                              hipStream_t stream) {
    const float* pts      = (const float*)d_in[0];   // (1,1024,32,3)
    const float* lidar    = (const float*)d_in[1];   // (1,8192,3)
    const float* features = (const float*)d_in[2];   // (1,8192,128)
    float* out = (float*)d_out;                      // (1,1024,32,128)

    char* ws = (char*)d_ws;
    unsigned long long* keys = (unsigned long long*)(ws + WS_KEYS);
    short* Btab = (short*)(ws + WS_BTAB);
    float4* cpack = (float4*)(ws + WS_CPK);

    prep_kernel<<<N_LIDAR / BLOCK, BLOCK, 0, stream>>>(lidar, Btab, cpack);
    fused_kernel<<<N_BLK, BLOCK, 0, stream>>>(
        pts, Btab, cpack, keys, (const float4*)features, (float4*)out);
}